// Round 5
// baseline (177.637 us; speedup 1.0000x reference)
//
#include <hip/hip_runtime.h>

// ---------------------------------------------------------------------------
// Pipeline (atomic-free edge path, no same-address global atomics anywhere):
//  A) k_passA: radix-partition edges by bucket=row>>shift into block-private
//     rec[block][bucket][CAP] regions (LDS returning atomics only).
//  B) k_passB<SUB>: per (bucket, chunk): prefix-sum segment lengths, binary-
//     search compacted iteration; LDS-accumulate per-node sums S=(Sx,Sea,Cnt);
//     write partials; pure-col Z moments (U) -> per-block partial STORE.
//  C) k_reduce: fold partials -> per-node means MSx; factorized Z moments (T)
//     -> per-block partial STORE.
//  Z) k_zfin: one block sums U/T partials -> ZC[54].
//  D) k_setup: assemble Z (10x10), fold BN1/BN2, build G (10x64), c0, kv.
//  E) k_nodesB: per node x1=relu(z.G+c0) -> P,Q scalars.
//  F) k_edges_out: e2 = relu(P[r]+Q[c]+ea*kv8+kv9).
// U/T partial buffers overlay the P region (P/Q are written only later).
// ---------------------------------------------------------------------------

#define NBLK_A 512

__global__ __launch_bounds__(256) void k_passA(
    const int* __restrict__ ei, const float* __restrict__ ea,
    int2* __restrict__ rec, int* __restrict__ len,
    int NB, int CAP, int shift, int SUBm, int E, int EPB)
{
    __shared__ int hist[128];
    int t = threadIdx.x;
    int blk = blockIdx.x;
    if (t < 128) hist[t] = 0;
    __syncthreads();
    int e0 = blk * EPB;
    int e1 = min(E, e0 + EPB);
    size_t base = (size_t)blk * NB;
    for (int e = e0 + t; e < e1; e += 256) {
        int r = ei[e];
        int c = ei[E + e];
        float a = ea[e];
        int b = r >> shift;
        int slot = atomicAdd(&hist[b], 1);
        if (slot < CAP) {
            int w0 = c | ((r & SUBm) << 17);
            rec[(base + b) * CAP + slot] = make_int2(w0, __float_as_int(a));
        }
    }
    __syncthreads();
    if (t < NB) len[base + t] = min(hist[t], CAP);
}

template <int SUB>
__global__ __launch_bounds__(256) void k_passB(
    const int2* __restrict__ rec, const int* __restrict__ len,
    const float4* __restrict__ x4, float* __restrict__ p,
    float* __restrict__ Up, int NB, int CAP, int CH)
{
    __shared__ __align__(16) float Sacc[SUB * 6];
    __shared__ int pre[129];
    __shared__ float red[16];
    int t = threadIdx.x;
    int b = blockIdx.x;
    int j = blockIdx.y;
    for (int k = t; k < SUB * 6; k += 256) Sacc[k] = 0.f;
    int s0 = (j * NBLK_A) / CH;
    int s1 = ((j + 1) * NBLK_A) / CH;
    int SEG = s1 - s0;
    if (t < SEG) pre[t + 1] = min(len[(size_t)(s0 + t) * NB + b], CAP);
    if (t == 0) pre[0] = 0;
    if (t < 16) red[t] = 0.f;
    __syncthreads();
    if (t == 0) {
        for (int i = 0; i < SEG; ++i) pre[i + 1] += pre[i];
    }
    __syncthreads();
    int R = pre[SEG];
    float u[15];
#pragma unroll
    for (int k = 0; k < 15; ++k) u[k] = 0.f;
    for (int idx = t; idx < R; idx += 256) {
        int lo = 0, hi = SEG;
        while (hi - lo > 1) {
            int mid = (lo + hi) >> 1;
            if (pre[mid] <= idx) lo = mid; else hi = mid;
        }
        int slot = idx - pre[lo];
        int2 v = rec[((size_t)(s0 + lo) * NB + b) * CAP + slot];
        int c = v.x & 0x1FFFF;
        int ridx = v.x >> 17;
        float a = __int_as_float(v.y);
        float4 xc = x4[c];
        atomicAdd(&Sacc[ridx * 6 + 0], xc.x);
        atomicAdd(&Sacc[ridx * 6 + 1], xc.y);
        atomicAdd(&Sacc[ridx * 6 + 2], xc.z);
        atomicAdd(&Sacc[ridx * 6 + 3], xc.w);
        atomicAdd(&Sacc[ridx * 6 + 4], a);
        atomicAdd(&Sacc[ridx * 6 + 5], 1.f);
        float zc[4] = {xc.x, xc.y, xc.z, xc.w};
        int q = 0;
#pragma unroll
        for (int i = 0; i < 4; ++i)
#pragma unroll
            for (int k = i; k < 4; ++k) { u[q] = fmaf(zc[i], zc[k], u[q]); ++q; }
#pragma unroll
        for (int i = 0; i < 4; ++i) u[10 + i] = fmaf(zc[i], a, u[10 + i]);
        u[14] = fmaf(a, a, u[14]);
    }
    __syncthreads();
    float4* pb = (float4*)(p + ((size_t)b * CH + j) * (SUB * 6));
    const float4* sa = (const float4*)Sacc;
    for (int k = t; k < SUB * 6 / 4; k += 256) pb[k] = sa[k];
    int lane = t & 63;
#pragma unroll
    for (int v = 0; v < 15; ++v) {
        float s = u[v];
#pragma unroll
        for (int off = 32; off > 0; off >>= 1) s += __shfl_down(s, off);
        if (lane == 0) atomicAdd(&red[v], s);
    }
    __syncthreads();
    // per-block partial store (NO same-address global atomics)
    if (t < 15) Up[(size_t)(b * CH + j) * 16 + t] = red[t];
}

__global__ __launch_bounds__(256) void k_reduce(
    const float* __restrict__ p, const float4* __restrict__ x4,
    float* __restrict__ MSx, float* __restrict__ Tp,
    int N, int shift, int SUBm, int CH)
{
    __shared__ float red[40];
    int t = threadIdx.x;
    int n = blockIdx.x * 256 + t;
    float Tacc[39];
#pragma unroll
    for (int k = 0; k < 39; ++k) Tacc[k] = 0.f;
    if (n < N) {
        int b = n >> shift;
        int i = n & SUBm;
        int SUB6 = (SUBm + 1) * 6;
        float S[6] = {0.f, 0.f, 0.f, 0.f, 0.f, 0.f};
        for (int j = 0; j < CH; ++j) {
            size_t base = ((size_t)b * CH + j) * SUB6 + (size_t)i * 6;
#pragma unroll
            for (int k = 0; k < 6; ++k) S[k] += p[base + k];
        }
        float4 xn = x4[n];
        float x[4] = {xn.x, xn.y, xn.z, xn.w};
        float cnt = S[5];
        int q = 0;
#pragma unroll
        for (int a = 0; a < 4; ++a)
#pragma unroll
            for (int bb = a; bb < 4; ++bb) { Tacc[q] = cnt * x[a] * x[bb]; ++q; }
#pragma unroll
        for (int a = 0; a < 4; ++a)
#pragma unroll
            for (int bb = 0; bb < 4; ++bb) Tacc[10 + a * 4 + bb] = x[a] * S[bb];
#pragma unroll
        for (int a = 0; a < 4; ++a) {
            Tacc[26 + a] = x[a] * S[4];
            Tacc[30 + a] = cnt * x[a];
            Tacc[34 + a] = S[a];
        }
        Tacc[38] = S[4];
        float inv = cnt > 0.f ? 1.f / cnt : 0.f;
        float4* m = (float4*)(MSx + (size_t)n * 8);
        m[0] = make_float4(S[0] * inv, S[1] * inv, S[2] * inv, S[3] * inv);
        m[1] = make_float4(S[4] * inv, cnt > 0.f ? 1.f : 0.f, 0.f, 0.f);
    }
    int lane = t & 63;
    if (t < 40) red[t] = 0.f;
    __syncthreads();
#pragma unroll
    for (int v = 0; v < 39; ++v) {
        float s = Tacc[v];
#pragma unroll
        for (int off = 32; off > 0; off >>= 1) s += __shfl_down(s, off);
        if (lane == 0) atomicAdd(&red[v], s);
    }
    __syncthreads();
    // per-block partial store (NO same-address global atomics)
    if (t < 39) Tp[(size_t)blockIdx.x * 40 + t] = red[t];
}

// single block: sum partials -> ZC[0..53] (T at 0..38, U at 39..53)
__global__ __launch_bounds__(256) void k_zfin(
    const float* __restrict__ Up, const float* __restrict__ Tp,
    float* __restrict__ ZC, int NBu, int NTb)
{
    __shared__ float red[64];
    int t = threadIdx.x;
    if (t < 64) red[t] = 0.f;
    __syncthreads();
    float u[15];
#pragma unroll
    for (int k = 0; k < 15; ++k) u[k] = 0.f;
    for (int i = t; i < NBu; i += 256) {
#pragma unroll
        for (int k = 0; k < 15; ++k) u[k] += Up[(size_t)i * 16 + k];
    }
    float tt[39];
#pragma unroll
    for (int k = 0; k < 39; ++k) tt[k] = 0.f;
    for (int i = t; i < NTb; i += 256) {
#pragma unroll
        for (int k = 0; k < 39; ++k) tt[k] += Tp[(size_t)i * 40 + k];
    }
    int lane = t & 63;
#pragma unroll
    for (int v = 0; v < 15; ++v) {
        float s = u[v];
#pragma unroll
        for (int off = 32; off > 0; off >>= 1) s += __shfl_down(s, off);
        if (lane == 0) atomicAdd(&red[39 + v], s);
    }
#pragma unroll
    for (int v = 0; v < 39; ++v) {
        float s = tt[v];
#pragma unroll
        for (int off = 32; off > 0; off >>= 1) s += __shfl_down(s, off);
        if (lane == 0) atomicAdd(&red[v], s);
    }
    __syncthreads();
    if (t < 54) ZC[t] = red[t];
}

__device__ __forceinline__ int sym4(int a, int b) {
    return a * 4 - a * (a - 1) / 2 + (b - a);
}

__global__ __launch_bounds__(128) void k_setup(
    const float* __restrict__ ZC,
    const float* __restrict__ We1, const float* __restrict__ be1,
    const float* __restrict__ g1, const float* __restrict__ bb1,
    const float* __restrict__ Wn1, const float* __restrict__ bn1,
    const float* __restrict__ g2, const float* __restrict__ bb2,
    const float* __restrict__ We2, const float* __restrict__ be2,
    const float* __restrict__ Wm2, const float* __restrict__ bm2,
    float* __restrict__ G, float* __restrict__ c0g, float* __restrict__ kvg,
    int E)
{
    __shared__ float Zf[100];
    __shared__ float s1[84], sh1[84];
    __shared__ float Ml[10 * 128];
    __shared__ float s2l[128], sh2l[128];
    int t = threadIdx.x;
    if (t < 100) {
        int i = t / 10, jj = t % 10;
        int a_ = i < jj ? i : jj;
        int b_ = i < jj ? jj : i;
        float v;
        if (b_ < 4) v = ZC[sym4(a_, b_)];
        else if (b_ < 8) {
            if (a_ < 4) v = ZC[10 + a_ * 4 + (b_ - 4)];
            else v = ZC[39 + sym4(a_ - 4, b_ - 4)];
        } else if (b_ == 8) {
            if (a_ < 4) v = ZC[26 + a_];
            else if (a_ < 8) v = ZC[49 + (a_ - 4)];
            else v = ZC[53];
        } else {
            if (a_ < 4) v = ZC[30 + a_];
            else if (a_ < 8) v = ZC[34 + (a_ - 4)];
            else if (a_ == 8) v = ZC[38];
            else v = (float)E;
        }
        Zf[t] = v;
    }
    __syncthreads();
    float Ef = (float)E;
    if (t < 84) {
        float w[10];
#pragma unroll
        for (int i = 0; i < 9; ++i) w[i] = We1[i * 84 + t];
        w[9] = be1[t];
        float sm = 0.f, sq = 0.f;
#pragma unroll
        for (int i = 0; i < 10; ++i) {
            sm += Zf[90 + i] * w[i];
            float zi = 0.f;
#pragma unroll
            for (int jj = 0; jj < 10; ++jj) zi += Zf[i * 10 + jj] * w[jj];
            sq += w[i] * zi;
        }
        float m = sm / Ef;
        float var = sq / Ef - m * m;
        float sc = g1[t] * rsqrtf(var + 1e-5f);
        s1[t] = sc;
        sh1[t] = bb1[t] - m * sc;
    }
    __syncthreads();
    if (t < 128) {
        float col[10];
#pragma unroll
        for (int i = 0; i < 10; ++i) col[i] = 0.f;
        for (int k = 0; k < 84; ++k) {
            float wn = Wn1[(4 + k) * 128 + t];
            float ws_ = s1[k] * wn;
#pragma unroll
            for (int i = 0; i < 9; ++i) col[i] = fmaf(We1[i * 84 + k], ws_, col[i]);
            col[9] += be1[k] * ws_ + sh1[k] * wn;
        }
#pragma unroll
        for (int i = 0; i < 4; ++i) col[4 + i] += Wn1[i * 128 + t];
        col[9] += bn1[t];
#pragma unroll
        for (int i = 0; i < 10; ++i) Ml[i * 128 + t] = col[i];
    }
    __syncthreads();
    if (t < 128) {
        float col[10];
#pragma unroll
        for (int i = 0; i < 10; ++i) col[i] = Ml[i * 128 + t];
        float sm = 0.f, sq = 0.f;
#pragma unroll
        for (int i = 0; i < 10; ++i) {
            sm += Zf[90 + i] * col[i];
            float zi = 0.f;
#pragma unroll
            for (int jj = 0; jj < 10; ++jj) zi += Zf[i * 10 + jj] * col[jj];
            sq += col[i] * zi;
        }
        float m = sm / Ef;
        float var = sq / Ef - m * m;
        float sc = g2[t] * rsqrtf(var + 1e-5f);
        s2l[t] = sc;
        sh2l[t] = bb2[t] - m * sc;
    }
    if (t < 10) {
        float kv = 0.f;
        if (t < 9) {
            for (int k = 0; k < 84; ++k)
                kv = fmaf(We1[t * 84 + k] * s1[k], We2[128 + k], kv);
        } else {
            for (int k = 0; k < 84; ++k)
                kv = fmaf(be1[k] * s1[k] + sh1[k], We2[128 + k], kv);
            kv += be2[0];
        }
        kvg[t] = kv;
    }
    __syncthreads();
    if (t < 64) {
        float gcol[10];
#pragma unroll
        for (int i = 0; i < 10; ++i) gcol[i] = 0.f;
        float c0 = 0.f;
        for (int k = 0; k < 128; ++k) {
            float bkj = Wm2[(4 + k) * 64 + t];
            float m = s2l[k] * bkj;
#pragma unroll
            for (int i = 0; i < 10; ++i) gcol[i] = fmaf(Ml[i * 128 + k], m, gcol[i]);
            c0 = fmaf(sh2l[k], bkj, c0);
        }
#pragma unroll
        for (int i = 0; i < 4; ++i) gcol[i] += Wm2[i * 64 + t];
        c0 += bm2[t];
#pragma unroll
        for (int i = 0; i < 10; ++i) G[i * 64 + t] = gcol[i];
        c0g[t] = c0;
    }
}

__global__ __launch_bounds__(256) void k_nodesB(
    const float4* __restrict__ x4, const float* __restrict__ MSx,
    const float* __restrict__ G, const float* __restrict__ c0g,
    const float* __restrict__ kv, const float* __restrict__ Wm2,
    const float* __restrict__ bm2, const float* __restrict__ We2,
    float* __restrict__ P, float* __restrict__ Q, int N)
{
    __shared__ float Gl[640], c0l[64], Al[256], bl[64], ul[64], vl[64], kvl[10];
    int t = threadIdx.x;
    for (int k = t; k < 640; k += 256) Gl[k] = G[k];
    if (t < 64) {
        c0l[t] = c0g[t];
        bl[t] = bm2[t];
        ul[t] = We2[t];
        vl[t] = We2[64 + t];
    }
    for (int k = t; k < 256; k += 256) Al[k] = Wm2[k];
    if (t < 10) kvl[t] = kv[t];
    __syncthreads();
    int n = blockIdx.x * 256 + t;
    if (n >= N) return;
    float4 xn = x4[n];
    const float4* m = (const float4*)(MSx + (size_t)n * 8);
    float4 m0 = m[0];
    float4 m1 = m[1];
    bool has = m1.y > 0.5f;
    float Pv = 0.f, Qv = 0.f;
    if (has) {
        float zb[10] = {xn.x, xn.y, xn.z, xn.w, m0.x, m0.y, m0.z, m0.w, m1.x, 1.f};
#pragma unroll 4
        for (int j = 0; j < 64; ++j) {
            float s = c0l[j];
#pragma unroll
            for (int i = 0; i < 10; ++i) s = fmaf(zb[i], Gl[i * 64 + j], s);
            s = fmaxf(s, 0.f);
            Pv = fmaf(s, ul[j], Pv);
            Qv = fmaf(s, vl[j], Qv);
        }
    } else {
#pragma unroll 4
        for (int j = 0; j < 64; ++j) {
            float s = bl[j] + xn.x * Al[j] + xn.y * Al[64 + j] +
                      xn.z * Al[128 + j] + xn.w * Al[192 + j];
            s = fmaxf(s, 0.f);
            Pv = fmaf(s, ul[j], Pv);
            Qv = fmaf(s, vl[j], Qv);
        }
    }
    P[n] = Pv + xn.x * kvl[0] + xn.y * kvl[1] + xn.z * kvl[2] + xn.w * kvl[3];
    Q[n] = Qv + xn.x * kvl[4] + xn.y * kvl[5] + xn.z * kvl[6] + xn.w * kvl[7];
}

__global__ __launch_bounds__(256) void k_edges_out(
    const int* __restrict__ ei, const float* __restrict__ ea,
    const float* __restrict__ P, const float* __restrict__ Q,
    const float* __restrict__ kv, float* __restrict__ out, int E)
{
    int e = blockIdx.x * 256 + threadIdx.x;
    if (e >= E) return;
    float s = P[ei[e]] + Q[ei[E + e]] + ea[e] * kv[8] + kv[9];
    out[e] = s > 0.f ? s : 0.f;
}

extern "C" void kernel_launch(void* const* d_in, const int* in_sizes, int n_in,
                              void* d_out, int out_size, void* d_ws, size_t ws_size,
                              hipStream_t stream)
{
    const float* x   = (const float*)d_in[0];
    const float* ea  = (const float*)d_in[1];
    const int*   ei  = (const int*)d_in[2];
    const float* We1 = (const float*)d_in[3];
    const float* be1 = (const float*)d_in[4];
    const float* g1  = (const float*)d_in[5];
    const float* bb1 = (const float*)d_in[6];
    const float* Wn1 = (const float*)d_in[7];
    const float* bn1 = (const float*)d_in[8];
    const float* g2  = (const float*)d_in[9];
    const float* bb2 = (const float*)d_in[10];
    const float* Wm2 = (const float*)d_in[11];
    const float* bm2 = (const float*)d_in[12];
    const float* We2 = (const float*)d_in[13];
    const float* be2 = (const float*)d_in[14];

    int N = in_sizes[0] / 4;
    int E = in_sizes[1];
    int EPB = (E + NBLK_A - 1) / NBLK_A;

    // config A: SUB=1024, CAP=96, CH=8 ; config B: SUB=2048, CAP=128, CH=6
    int NB_A = (N + 1023) >> 10;
    int NB_B = (N + 2047) >> 11;
    size_t headf = 1024 + 10 * (size_t)N;  // ZC..kv + P + Q + MSx
    size_t need_A = (headf + (size_t)NBLK_A * NB_A * (1 + 2 * 96) +
                     (size_t)NB_A * 8 * 1024 * 6) * 4;
    bool useA = ws_size >= need_A;
    int NB    = useA ? NB_A : NB_B;
    int CAP   = useA ? 96 : 128;
    int CH    = useA ? 8 : 6;
    int shift = useA ? 10 : 11;
    int SUBm  = useA ? 1023 : 2047;

    float* ws  = (float*)d_ws;
    float* ZC  = ws;              // 64 (54 used)
    float* G   = ws + 64;         // 640
    float* c0  = ws + 704;        // 64
    float* kv  = ws + 768;        // 16 (pad to 1024)
    float* P   = ws + 1024;       // N
    float* Q   = P + N;           // N
    float* MSx = Q + N;           // 8N
    int*   len = (int*)(MSx + 8 * (size_t)N);          // NBLK_A*NB
    int2*  rec = (int2*)(len + (size_t)NBLK_A * NB);   // NBLK_A*NB*CAP
    float* prt = (float*)(rec + (size_t)NBLK_A * NB * CAP); // NB*CH*SUB*6

    // U/T partial buffers overlay P (P/Q written only by k_nodesB, later)
    float* Up = P;                // NB*CH*16 floats
    float* Tp = P + 32768;        // NTb*40 floats
    int NBu = NB * CH;
    int NTb = (N + 255) / 256;

    k_passA<<<NBLK_A, 256, 0, stream>>>(ei, ea, rec, len, NB, CAP, shift,
                                        SUBm, E, EPB);
    if (useA)
        k_passB<1024><<<dim3(NB, CH), 256, 0, stream>>>(rec, len,
            (const float4*)x, prt, Up, NB, CAP, CH);
    else
        k_passB<2048><<<dim3(NB, CH), 256, 0, stream>>>(rec, len,
            (const float4*)x, prt, Up, NB, CAP, CH);
    k_reduce<<<NTb, 256, 0, stream>>>(prt, (const float4*)x, MSx, Tp, N,
                                      shift, SUBm, CH);
    k_zfin<<<1, 256, 0, stream>>>(Up, Tp, ZC, NBu, NTb);
    k_setup<<<1, 128, 0, stream>>>(ZC, We1, be1, g1, bb1, Wn1, bn1, g2, bb2,
                                   We2, be2, Wm2, bm2, G, c0, kv, E);
    k_nodesB<<<(N + 255) / 256, 256, 0, stream>>>((const float4*)x, MSx, G,
                                                  c0, kv, Wm2, bm2, We2, P, Q,
                                                  N);
    k_edges_out<<<(E + 255) / 256, 256, 0, stream>>>(ei, ea, P, Q, kv,
                                                     (float*)d_out, E);
}